// Round 2
// baseline (122.763 us; speedup 1.0000x reference)
//
#include <hip/hip_runtime.h>
#include <hip/hip_fp16.h>

// ============================================================================
// JResCOPAttn  (B=1, L=1024, D=128, fp32)
//
//   a  = x@Wl.T+bl ; tx = x@Wl2.T+bl2
//   tm[l,m,d] = sum_e a[l,e]*a[m,e]*Wlo[d,e] + blo[d]
//   y[l,d]    = x[l,d] + sum_m mask[l,m]*tm[l,m,d]*tx[m,d]  -> LayerNorm_d
//
// Dominant cost: 2*L^2*D^2 = 34.4 GFLOP GEMM (M=L^2 pairs, N=K=D=128).
// Round 2: (a) FIX round-1 bug: ash staging loaded 2048/8192 elements.
//          (b) 1-term f16 MFMA (threshold is 9.06e-2; est. max err ~5e-3,
//              ~50x margin) — 3x fewer MFMAs than round 1.
//          (c) N=64 per wave (block = 32l x 64m x 128d, waves = 2l x 2d):
//              amortizes P-fragment build over 4x more MFMAs than N=32.
//          (d) A-build in f16: P = pk_mul(a_l_f16, a_m_f16); a stored f16.
// ============================================================================

typedef _Float16 f16x8 __attribute__((ext_vector_type(8)));
typedef float    f32x4 __attribute__((ext_vector_type(4)));

#define LL   1024
#define DD   128
#define EPSV 1e-5f

// ---------------------------------------------------------------------------
// prep: a = (f16)(x@Wl.T + bl) ; tx = x@Wl2.T + bl2 ; wh = (f16)Wlo
// grid (4,64) x 256 : bx in {0,1} -> a cols [bx*64,..) ; {2,3} -> tx cols
// ---------------------------------------------------------------------------
__global__ __launch_bounds__(256) void prep_kernel(
    const float* __restrict__ x,  const float* __restrict__ Wl,
    const float* __restrict__ bl, const float* __restrict__ Wlo,
    const float* __restrict__ Wl2,const float* __restrict__ bl2,
    _Float16* __restrict__ a_h, float* __restrict__ tx_out,
    _Float16* __restrict__ wh)
{
    __shared__ float xs[16*128];
    __shared__ float wsh[64*132];          // +4 float pad: b128 conflict floor
    const int t  = threadIdx.x;
    const int bx = blockIdx.x;
    const int by = blockIdx.y;
    const int l0 = by*16;

    #pragma unroll
    for (int i = 0; i < 8; ++i) { int f = i*256 + t; xs[f] = x[l0*DD + f]; }
    const float* Wsrc = ((bx < 2) ? Wl : Wl2) + (bx & 1)*64*DD;
    #pragma unroll
    for (int i = 0; i < 32; ++i) {
        int f = i*256 + t; int r = f >> 7, k = f & 127;
        wsh[r*132 + k] = Wsrc[f];
    }
    __syncthreads();

    const int col  = t & 63;               // output column within 64-chunk
    const int lsub = t >> 6;               // 4-row l group
    const float4* W4 = (const float4*)wsh;
    const float4* X4 = (const float4*)xs;
    float acc0 = 0.f, acc1 = 0.f, acc2 = 0.f, acc3 = 0.f;
    #pragma unroll
    for (int k4 = 0; k4 < 32; ++k4) {
        float4 wv = W4[col*33 + k4];
        float4 x0 = X4[(lsub*4+0)*32 + k4];
        float4 x1 = X4[(lsub*4+1)*32 + k4];
        float4 x2 = X4[(lsub*4+2)*32 + k4];
        float4 x3 = X4[(lsub*4+3)*32 + k4];
        acc0 += wv.x*x0.x + wv.y*x0.y + wv.z*x0.z + wv.w*x0.w;
        acc1 += wv.x*x1.x + wv.y*x1.y + wv.z*x1.z + wv.w*x1.w;
        acc2 += wv.x*x2.x + wv.y*x2.y + wv.z*x2.z + wv.w*x2.w;
        acc3 += wv.x*x3.x + wv.y*x3.y + wv.z*x3.z + wv.w*x3.w;
    }
    const int colg = (bx & 1)*64 + col;
    const float bv = ((bx < 2) ? bl : bl2)[colg];
    if (bx < 2) {
        a_h[(l0+lsub*4+0)*DD + colg] = (_Float16)(acc0 + bv);
        a_h[(l0+lsub*4+1)*DD + colg] = (_Float16)(acc1 + bv);
        a_h[(l0+lsub*4+2)*DD + colg] = (_Float16)(acc2 + bv);
        a_h[(l0+lsub*4+3)*DD + colg] = (_Float16)(acc3 + bv);
    } else {
        tx_out[(l0+lsub*4+0)*DD + colg] = acc0 + bv;
        tx_out[(l0+lsub*4+1)*DD + colg] = acc1 + bv;
        tx_out[(l0+lsub*4+2)*DD + colg] = acc2 + bv;
        tx_out[(l0+lsub*4+3)*DD + colg] = acc3 + bv;
    }

    const int gid = (by*4 + bx)*256 + t;   // Wlo -> f16, once
    if (gid < DD*DD) wh[gid] = (_Float16)Wlo[gid];
}

// ---------------------------------------------------------------------------
// heavy: block = (chunk: 64 m's) x (ltile: 32 l's) x all 128 d.
// 4 waves: w>>1 = l-half (16 l's), w&1 = d-half (64 d's = 4 n-frags).
// Per m: A-frags P[l,e]=a_l[e]*a_m[e] via v_pk_mul_f16; 16 MFMAs; fold
// mask*tx*(tm+blo) into per-lane fp32 y accumulators. fp32 partials out.
// ---------------------------------------------------------------------------
__global__ __launch_bounds__(256, 2) void heavy_kernel(
    const _Float16* __restrict__ a_h, const float* __restrict__ tx,
    const _Float16* __restrict__ wh,  const int* __restrict__ mask,
    const float* __restrict__ blo,    float* __restrict__ part)
{
    __shared__ __align__(16) _Float16 ash[64*DD];   // 16 KB, f16 a m-rows
    const int t     = threadIdx.x;
    const int lane  = t & 63, w = t >> 6;
    const int chunk = blockIdx.x;          // 0..15
    const int ltile = blockIdx.y;          // 0..31
    const int l0 = ltile*32, m0 = chunk*64;

    {   // stage 64 m-rows of f16 a: 16 KB = 1024 float4 = 4 per thread
        const float4* s4 = (const float4*)(a_h + m0*DD);
        float4* d4 = (float4*)ash;
        #pragma unroll
        for (int i = 0; i < 4; ++i) d4[i*256 + t] = s4[i*256 + t];
    }
    __syncthreads();

    const int grp = lane >> 4, ln = lane & 15;
    const int wl = w >> 1, wd = w & 1;
    const int lbase = l0 + wl*16;          // this wave's 16 l rows
    const int dbase = wd*64;               // this wave's 64 d cols

    // B fragments (constant): B[e,d]=Wlo[d,e]; frag: col=lane&15, k=(lane>>4)*8+j
    f16x8 bh[4][4];
    #pragma unroll
    for (int nf = 0; nf < 4; ++nf)
        #pragma unroll
        for (int k = 0; k < 4; ++k)
            bh[nf][k] = *(const f16x8*)(wh + (dbase + nf*16 + ln)*DD + k*32 + grp*8);

    // this lane's a_l (A-frag row = lane&15 = l)
    f16x8 al[4];
    #pragma unroll
    for (int k = 0; k < 4; ++k)
        al[k] = *(const f16x8*)(a_h + (lbase + ln)*DD + k*32 + grp*8);

    float blov[4];
    #pragma unroll
    for (int nf = 0; nf < 4; ++nf) blov[nf] = blo[dbase + nf*16 + ln];

    f32x4 y[4] = {{0,0,0,0},{0,0,0,0},{0,0,0,0},{0,0,0,0}};
    const int mrow0 = lbase + grp*4;       // C-frag rows: (lane>>4)*4 + reg

    for (int ml = 0; ml < 64; ++ml) {
        const int mg = m0 + ml;
        // fold operands early (L1/L2 broadcast loads, hidden under MFMA)
        float txd[4];
        #pragma unroll
        for (int nf = 0; nf < 4; ++nf) txd[nf] = tx[mg*DD + dbase + nf*16 + ln];
        float wm[4];
        #pragma unroll
        for (int r = 0; r < 4; ++r)
            wm[r] = (mask[(mrow0 + r)*LL + mg] != 0) ? 1.f : 0.f;

        // A-frags: P = a_l * a_m in f16 (v_pk_mul_f16)
        f16x8 ah[4];
        #pragma unroll
        for (int k = 0; k < 4; ++k) {
            f16x8 q = *(const f16x8*)(ash + ml*DD + k*32 + grp*8);  // 16-lane bcast
            ah[k] = al[k] * q;
        }

        f32x4 c[4] = {{0,0,0,0},{0,0,0,0},{0,0,0,0},{0,0,0,0}};
        #pragma unroll
        for (int k = 0; k < 4; ++k) {
            c[0] = __builtin_amdgcn_mfma_f32_16x16x32_f16(ah[k], bh[0][k], c[0], 0,0,0);
            c[1] = __builtin_amdgcn_mfma_f32_16x16x32_f16(ah[k], bh[1][k], c[1], 0,0,0);
            c[2] = __builtin_amdgcn_mfma_f32_16x16x32_f16(ah[k], bh[2][k], c[2], 0,0,0);
            c[3] = __builtin_amdgcn_mfma_f32_16x16x32_f16(ah[k], bh[3][k], c[3], 0,0,0);
        }
        // y[l,d] += mask[l,m]*tx[m,d]*(tm_raw + blo[d])
        #pragma unroll
        for (int nf = 0; nf < 4; ++nf)
            #pragma unroll
            for (int r = 0; r < 4; ++r)
                y[nf][r] += (wm[r]*txd[nf]) * (c[nf][r] + blov[nf]);
    }

    // part[chunk][l][d], fp32
    float* dst = part + (size_t)chunk*(LL*DD);
    #pragma unroll
    for (int nf = 0; nf < 4; ++nf)
        #pragma unroll
        for (int r = 0; r < 4; ++r)
            dst[(mrow0 + r)*DD + dbase + nf*16 + ln] = y[nf][r];
}

// ---------------------------------------------------------------------------
// finish: y = x + sum_chunks part ; LayerNorm over d. grid 1024 x 128.
// ---------------------------------------------------------------------------
__global__ __launch_bounds__(128) void finish_kernel(
    const float* __restrict__ x, const float* __restrict__ part,
    const float* __restrict__ gamma, const float* __restrict__ beta,
    float* __restrict__ out)
{
    const int l = blockIdx.x, t = threadIdx.x;
    float v = x[l*DD + t];
    #pragma unroll
    for (int ch = 0; ch < 16; ++ch)
        v += part[((size_t)ch*LL + l)*DD + t];

    float s = v, s2 = v*v;
    #pragma unroll
    for (int o = 32; o > 0; o >>= 1) {     // wave64 butterfly
        s  += __shfl_xor(s, o);
        s2 += __shfl_xor(s2, o);
    }
    __shared__ float red[4];
    if ((t & 63) == 0) { red[(t>>6)*2+0] = s; red[(t>>6)*2+1] = s2; }
    __syncthreads();
    const float S  = red[0] + red[2];
    const float S2 = red[1] + red[3];
    const float mu  = S * (1.0f/128.0f);
    const float var = S2 * (1.0f/128.0f) - mu*mu;
    const float inv = rsqrtf(var + EPSV);
    out[l*DD + t] = (v - mu)*inv*gamma[t] + beta[t];
}

// ---------------------------------------------------------------------------
extern "C" void kernel_launch(void* const* d_in, const int* in_sizes, int n_in,
                              void* d_out, int out_size, void* d_ws, size_t ws_size,
                              hipStream_t stream)
{
    (void)in_sizes; (void)n_in; (void)out_size; (void)ws_size;
    const float* x     = (const float*)d_in[0];
    const int*   mask  = (const int*)  d_in[1];
    const float* Wl    = (const float*)d_in[2];
    const float* bl    = (const float*)d_in[3];
    const float* Wlo   = (const float*)d_in[4];
    const float* blo   = (const float*)d_in[5];
    const float* Wl2   = (const float*)d_in[6];
    const float* bl2   = (const float*)d_in[7];
    const float* gamma = (const float*)d_in[8];
    const float* beta  = (const float*)d_in[9];
    float* out = (float*)d_out;

    // ws layout (9 MB): a_h f16 256K | tx f32 512K | wh f16 32K | part 8M @1M
    char* ws = (char*)d_ws;
    _Float16* a_h  = (_Float16*)(ws);
    float*    tx_b = (float*)   (ws + (256u<<10));
    _Float16* wh   = (_Float16*)(ws + (768u<<10));
    float*    part = (float*)   (ws + (1024u<<10));

    prep_kernel  <<<dim3(4,64),  256, 0, stream>>>(x, Wl, bl, Wlo, Wl2, bl2,
                                                   a_h, tx_b, wh);
    heavy_kernel <<<dim3(16,32), 256, 0, stream>>>(a_h, tx_b, wh, mask, blo, part);
    finish_kernel<<<1024, 128, 0, stream>>>(x, part, gamma, beta, out);
}

// Round 3
// 117.530 us; speedup vs baseline: 1.0445x; 1.0445x over previous
//
#include <hip/hip_runtime.h>
#include <hip/hip_fp16.h>

// ============================================================================
// JResCOPAttn  (B=1, L=1024, D=128, fp32)
//
//   a  = x@Wl.T+bl ; tx = x@Wl2.T+bl2
//   tm[l,m,d] = sum_e a[l,e]*a[m,e]*Wlo[d,e] + blo[d]
//   y[l,d]    = x[l,d] + sum_m mask[l,m]*tm[l,m,d]*tx[m,d]  -> LayerNorm_d
//
// Round 3 (from round-2 counters: MfmaUtil 26.6 / VALUBusy 31 / ~930 cyc per
// m-iter => global-load latency-bound in the inner loop):
//   (a) Stage tx (f32) and mask (as 0/1 f32) into LDS once per block; inner
//       loop is now LDS+reg only.  LDS = 16K ash + 32K txsh + 8K wmsh = 56KB.
//   (b) Defer blo: y += s*c with s = wm*txd accumulated into S; final
//       y += blo*S.  Saves 16 VALU/iter.
//   (c) prep: wsh stride 132 dwords (== 4 mod 32, 8-way conflict) -> stride
//       129 scalar reads (conflict-free).
//   (d) #pragma unroll 2 on m-loop for cross-iter scheduling room.
// ============================================================================

typedef _Float16 f16x8 __attribute__((ext_vector_type(8)));
typedef float    f32x4 __attribute__((ext_vector_type(4)));

#define LL   1024
#define DD   128
#define EPSV 1e-5f

// ---------------------------------------------------------------------------
// prep: a_h = (f16)(x@Wl.T + bl) ; tx = x@Wl2.T + bl2 ; wh = (f16)Wlo
// grid (4,64) x 256 : bx in {0,1} -> a cols [bx*64,..) ; {2,3} -> tx cols
// ---------------------------------------------------------------------------
__global__ __launch_bounds__(256) void prep_kernel(
    const float* __restrict__ x,  const float* __restrict__ Wl,
    const float* __restrict__ bl, const float* __restrict__ Wlo,
    const float* __restrict__ Wl2,const float* __restrict__ bl2,
    _Float16* __restrict__ a_h, float* __restrict__ tx_out,
    _Float16* __restrict__ wh)
{
    __shared__ float xs[16*128];
    __shared__ float wsh[64*129];          // stride 129 dwords: conflict-free
    const int t  = threadIdx.x;
    const int bx = blockIdx.x;
    const int by = blockIdx.y;
    const int l0 = by*16;

    #pragma unroll
    for (int i = 0; i < 8; ++i) { int f = i*256 + t; xs[f] = x[l0*DD + f]; }
    const float* Wsrc = ((bx < 2) ? Wl : Wl2) + (bx & 1)*64*DD;
    #pragma unroll
    for (int i = 0; i < 32; ++i) {
        int f = i*256 + t; int r = f >> 7, k = f & 127;
        wsh[r*129 + k] = Wsrc[f];
    }
    __syncthreads();

    const int col  = t & 63;               // output column within 64-chunk
    const int lsub = t >> 6;               // 4-row l group
    const float4* X4 = (const float4*)xs;
    float acc0 = 0.f, acc1 = 0.f, acc2 = 0.f, acc3 = 0.f;
    #pragma unroll
    for (int k4 = 0; k4 < 32; ++k4) {
        const float* wp = wsh + col*129 + k4*4;
        float4 wv = {wp[0], wp[1], wp[2], wp[3]};   // distinct banks per lane
        float4 x0 = X4[(lsub*4+0)*32 + k4];         // broadcast within wave
        float4 x1 = X4[(lsub*4+1)*32 + k4];
        float4 x2 = X4[(lsub*4+2)*32 + k4];
        float4 x3 = X4[(lsub*4+3)*32 + k4];
        acc0 += wv.x*x0.x + wv.y*x0.y + wv.z*x0.z + wv.w*x0.w;
        acc1 += wv.x*x1.x + wv.y*x1.y + wv.z*x1.z + wv.w*x1.w;
        acc2 += wv.x*x2.x + wv.y*x2.y + wv.z*x2.z + wv.w*x2.w;
        acc3 += wv.x*x3.x + wv.y*x3.y + wv.z*x3.z + wv.w*x3.w;
    }
    const int colg = (bx & 1)*64 + col;
    const float bv = ((bx < 2) ? bl : bl2)[colg];
    if (bx < 2) {
        a_h[(l0+lsub*4+0)*DD + colg] = (_Float16)(acc0 + bv);
        a_h[(l0+lsub*4+1)*DD + colg] = (_Float16)(acc1 + bv);
        a_h[(l0+lsub*4+2)*DD + colg] = (_Float16)(acc2 + bv);
        a_h[(l0+lsub*4+3)*DD + colg] = (_Float16)(acc3 + bv);
    } else {
        tx_out[(l0+lsub*4+0)*DD + colg] = acc0 + bv;
        tx_out[(l0+lsub*4+1)*DD + colg] = acc1 + bv;
        tx_out[(l0+lsub*4+2)*DD + colg] = acc2 + bv;
        tx_out[(l0+lsub*4+3)*DD + colg] = acc3 + bv;
    }

    const int gid = (by*4 + bx)*256 + t;   // Wlo -> f16, once
    if (gid < DD*DD) wh[gid] = (_Float16)Wlo[gid];
}

// ---------------------------------------------------------------------------
// heavy: block = (chunk: 64 m's) x (ltile: 32 l's) x all 128 d.
// 4 waves: w>>1 = l-half (16 l's), w&1 = d-half (64 d's = 4 n-frags).
// All inner-loop operands staged in LDS; per m: A-frags via v_pk_mul_f16,
// 16 MFMAs, fold s=wm*tx into y (+S for deferred blo). fp32 partials out.
// ---------------------------------------------------------------------------
__global__ __launch_bounds__(256, 2) void heavy_kernel(
    const _Float16* __restrict__ a_h, const float* __restrict__ tx,
    const _Float16* __restrict__ wh,  const int* __restrict__ mask,
    const float* __restrict__ blo,    float* __restrict__ part)
{
    __shared__ __align__(16) _Float16 ash[64*DD];   // 16 KB
    __shared__ __align__(16) float    txsh[64*DD];  // 32 KB
    __shared__ float                  wmsh[32*64];  //  8 KB
    const int t     = threadIdx.x;
    const int lane  = t & 63, w = t >> 6;
    const int chunk = blockIdx.x;          // 0..15
    const int ltile = blockIdx.y;          // 0..31
    const int l0 = ltile*32, m0 = chunk*64;

    {   // ash: 16 KB = 1024 float4
        const float4* s4 = (const float4*)(a_h + m0*DD);
        float4* d4 = (float4*)ash;
        #pragma unroll
        for (int i = 0; i < 4; ++i) d4[i*256 + t] = s4[i*256 + t];
    }
    {   // txsh: 32 KB = 2048 float4
        const float4* s4 = (const float4*)(tx + m0*DD);
        float4* d4 = (float4*)txsh;
        #pragma unroll
        for (int i = 0; i < 8; ++i) d4[i*256 + t] = s4[i*256 + t];
    }
    {   // wmsh: mask[(l0+row)][m0+col] -> 0/1 float
        #pragma unroll
        for (int i = 0; i < 8; ++i) {
            int idx = i*256 + t;
            int row = idx >> 6, colm = idx & 63;
            wmsh[idx] = (mask[(l0 + row)*LL + m0 + colm] != 0) ? 1.f : 0.f;
        }
    }
    __syncthreads();

    const int grp = lane >> 4, ln = lane & 15;
    const int wl = w >> 1, wd = w & 1;
    const int lbase = l0 + wl*16;          // this wave's 16 l rows
    const int dbase = wd*64;               // this wave's 64 d cols

    // B fragments (constant): B[e,d]=Wlo[d,e]; frag: col=lane&15, k=(lane>>4)*8+j
    f16x8 bh[4][4];
    #pragma unroll
    for (int nf = 0; nf < 4; ++nf)
        #pragma unroll
        for (int k = 0; k < 4; ++k)
            bh[nf][k] = *(const f16x8*)(wh + (dbase + nf*16 + ln)*DD + k*32 + grp*8);

    // this lane's a_l (A-frag row = lane&15 = l)
    f16x8 al[4];
    #pragma unroll
    for (int k = 0; k < 4; ++k)
        al[k] = *(const f16x8*)(a_h + (lbase + ln)*DD + k*32 + grp*8);

    float blov[4];
    #pragma unroll
    for (int nf = 0; nf < 4; ++nf) blov[nf] = blo[dbase + nf*16 + ln];

    f32x4 y[4] = {{0,0,0,0},{0,0,0,0},{0,0,0,0},{0,0,0,0}};
    f32x4 S[4] = {{0,0,0,0},{0,0,0,0},{0,0,0,0},{0,0,0,0}};
    const int mrow0 = lbase + grp*4;       // C-frag rows: (lane>>4)*4 + reg
    const int wmbase = (wl*16 + grp*4)*64; // wm rows for this lane

    #pragma unroll 2
    for (int ml = 0; ml < 64; ++ml) {
        float txd[4];
        #pragma unroll
        for (int nf = 0; nf < 4; ++nf) txd[nf] = txsh[ml*DD + dbase + nf*16 + ln];
        float wm[4];
        #pragma unroll
        for (int r = 0; r < 4; ++r) wm[r] = wmsh[wmbase + r*64 + ml];

        // A-frags: P = a_l * a_m in f16 (v_pk_mul_f16), a_m broadcast from LDS
        f16x8 ah[4];
        #pragma unroll
        for (int k = 0; k < 4; ++k)
            ah[k] = al[k] * *(const f16x8*)(ash + ml*DD + k*32 + grp*8);

        f32x4 c[4] = {{0,0,0,0},{0,0,0,0},{0,0,0,0},{0,0,0,0}};
        #pragma unroll
        for (int k = 0; k < 4; ++k) {
            c[0] = __builtin_amdgcn_mfma_f32_16x16x32_f16(ah[k], bh[0][k], c[0], 0,0,0);
            c[1] = __builtin_amdgcn_mfma_f32_16x16x32_f16(ah[k], bh[1][k], c[1], 0,0,0);
            c[2] = __builtin_amdgcn_mfma_f32_16x16x32_f16(ah[k], bh[2][k], c[2], 0,0,0);
            c[3] = __builtin_amdgcn_mfma_f32_16x16x32_f16(ah[k], bh[3][k], c[3], 0,0,0);
        }
        // y += (wm*tx)*c ;  S += wm*tx  (blo folded after the loop)
        #pragma unroll
        for (int nf = 0; nf < 4; ++nf)
            #pragma unroll
            for (int r = 0; r < 4; ++r) {
                float s = wm[r]*txd[nf];
                y[nf][r] = fmaf(s, c[nf][r], y[nf][r]);
                S[nf][r] += s;
            }
    }

    // part[chunk][l][d], fp32 ; y_total = y + blo*S
    float* dst = part + (size_t)chunk*(LL*DD);
    #pragma unroll
    for (int nf = 0; nf < 4; ++nf)
        #pragma unroll
        for (int r = 0; r < 4; ++r)
            dst[(mrow0 + r)*DD + dbase + nf*16 + ln] =
                fmaf(blov[nf], S[nf][r], y[nf][r]);
}

// ---------------------------------------------------------------------------
// finish: y = x + sum_chunks part ; LayerNorm over d. grid 1024 x 128.
// ---------------------------------------------------------------------------
__global__ __launch_bounds__(128) void finish_kernel(
    const float* __restrict__ x, const float* __restrict__ part,
    const float* __restrict__ gamma, const float* __restrict__ beta,
    float* __restrict__ out)
{
    const int l = blockIdx.x, t = threadIdx.x;
    float v = x[l*DD + t];
    #pragma unroll
    for (int ch = 0; ch < 16; ++ch)
        v += part[((size_t)ch*LL + l)*DD + t];

    float s = v, s2 = v*v;
    #pragma unroll
    for (int o = 32; o > 0; o >>= 1) {     // wave64 butterfly
        s  += __shfl_xor(s, o);
        s2 += __shfl_xor(s2, o);
    }
    __shared__ float red[4];
    if ((t & 63) == 0) { red[(t>>6)*2+0] = s; red[(t>>6)*2+1] = s2; }
    __syncthreads();
    const float S  = red[0] + red[2];
    const float S2 = red[1] + red[3];
    const float mu  = S * (1.0f/128.0f);
    const float var = S2 * (1.0f/128.0f) - mu*mu;
    const float inv = rsqrtf(var + EPSV);
    out[l*DD + t] = (v - mu)*inv*gamma[t] + beta[t];
}

// ---------------------------------------------------------------------------
extern "C" void kernel_launch(void* const* d_in, const int* in_sizes, int n_in,
                              void* d_out, int out_size, void* d_ws, size_t ws_size,
                              hipStream_t stream)
{
    (void)in_sizes; (void)n_in; (void)out_size; (void)ws_size;
    const float* x     = (const float*)d_in[0];
    const int*   mask  = (const int*)  d_in[1];
    const float* Wl    = (const float*)d_in[2];
    const float* bl    = (const float*)d_in[3];
    const float* Wlo   = (const float*)d_in[4];
    const float* blo   = (const float*)d_in[5];
    const float* Wl2   = (const float*)d_in[6];
    const float* bl2   = (const float*)d_in[7];
    const float* gamma = (const float*)d_in[8];
    const float* beta  = (const float*)d_in[9];
    float* out = (float*)d_out;

    // ws layout (9 MB): a_h f16 256K | tx f32 512K | wh f16 32K | part 8M @1M
    char* ws = (char*)d_ws;
    _Float16* a_h  = (_Float16*)(ws);
    float*    tx_b = (float*)   (ws + (256u<<10));
    _Float16* wh   = (_Float16*)(ws + (768u<<10));
    float*    part = (float*)   (ws + (1024u<<10));

    prep_kernel  <<<dim3(4,64),  256, 0, stream>>>(x, Wl, bl, Wlo, Wl2, bl2,
                                                   a_h, tx_b, wh);
    heavy_kernel <<<dim3(16,32), 256, 0, stream>>>(a_h, tx_b, wh, mask, blo, part);
    finish_kernel<<<1024, 128, 0, stream>>>(x, part, gamma, beta, out);
}